// Round 1
// baseline (168.813 us; speedup 1.0000x reference)
//
#include <hip/hip_runtime.h>

#define N_SEL 8192
#define SUB_SZ 32
#define N_SUB 256
#define N_GRAPH 64
#define N_FULL 12288
#define E_RAW 262144
#define N_PERS 4
#define D 128
#define EPSILON 0.1f
#define LAMB1 0.5f

// One block (256 threads) per subgraph: compute the 32x32 weighted-cosine
// block, threshold, row-scale, and scatter nonzeros into the dense output.
__global__ __launch_bounds__(256) void subgraph_kernel(
        const float* __restrict__ x,          // [N_SEL, D]
        const float* __restrict__ Wc,         // [N_PERS, D]
        const float* __restrict__ sscore,     // [N_SUB]
        const int*   __restrict__ smap,       // [N_SEL]
        float* __restrict__ out)              // [N_FULL, N_FULL], pre-zeroed
{
    const int s    = blockIdx.x;      // subgraph id
    const int base = s * SUB_SZ;
    const int tid  = threadIdx.x;

    __shared__ float xs[SUB_SZ][D + 1];        // +1 pad: conflict-free column reads
    __shared__ float w2[N_PERS][D];            // Wc^2
    __shared__ float rnorm[N_PERS][SUB_SZ];    // 1/norm per (perspective, node)
    __shared__ int   map_s[SUB_SZ];
    __shared__ float rowscore;

    // stage x tile (32x128 floats), coalesced global reads
    for (int k = tid; k < SUB_SZ * D; k += 256) {
        int i = k >> 7;        // k / 128
        int d = k & (D - 1);   // k % 128
        xs[i][d] = x[(base + i) * D + d];
    }
    // Wc^2
    for (int k = tid; k < N_PERS * D; k += 256) {
        float w = Wc[k];
        ((float*)w2)[k] = w * w;
    }
    if (tid < SUB_SZ) map_s[tid] = smap[base + tid];
    if (tid == 0) {
        int g4 = (s >> 2) << 2;   // first subgraph of this graph
        float sum = sscore[g4] + sscore[g4 + 1] + sscore[g4 + 2] + sscore[g4 + 3];
        rowscore = (sscore[s] / sum) * LAMB1;
    }
    __syncthreads();

    // per-(perspective, node) inverse norms: 128 tasks
    if (tid < N_PERS * SUB_SZ) {
        int p = tid >> 5;
        int i = tid & 31;
        float acc = 0.f;
        #pragma unroll 8
        for (int d = 0; d < D; ++d) {
            float v = xs[i][d];
            acc = fmaf(v * v, w2[p][d], acc);
        }
        float n = fmaxf(sqrtf(acc), 1e-12f);
        rnorm[p][i] = 1.0f / n;
    }
    __syncthreads();

    // 1024 (i,j) entries, 4 per thread
    for (int e = tid; e < SUB_SZ * SUB_SZ; e += 256) {
        int i = e >> 5;
        int j = e & 31;
        if (i == j) continue;                  // RemoveSelfLoop
        float a0 = 0.f, a1 = 0.f, a2 = 0.f, a3 = 0.f;
        #pragma unroll 8
        for (int d = 0; d < D; ++d) {
            float prod = xs[i][d] * xs[j][d];
            a0 = fmaf(prod, w2[0][d], a0);
            a1 = fmaf(prod, w2[1][d], a1);
            a2 = fmaf(prod, w2[2][d], a2);
            a3 = fmaf(prod, w2[3][d], a3);
        }
        float adj = 0.25f * (a0 * rnorm[0][i] * rnorm[0][j] +
                             a1 * rnorm[1][i] * rnorm[1][j] +
                             a2 * rnorm[2][i] * rnorm[2][j] +
                             a3 * rnorm[3][i] * rnorm[3][j]);
        if (adj > EPSILON) {                   // EpsilonNN (zeros skipped: out pre-zeroed)
            long long row = map_s[i];
            long long col = map_s[j];
            out[row * (long long)N_FULL + col] = adj * rowscore;  // unique targets
        }
    }
}

__global__ __launch_bounds__(256) void raw_edge_kernel(
        const int* __restrict__ ei, float* __restrict__ out)
{
    int e = blockIdx.x * blockDim.x + threadIdx.x;
    if (e < E_RAW) {
        long long r = ei[e];
        long long c = ei[E_RAW + e];
        atomicAdd(&out[r * (long long)N_FULL + c], 1.0f - LAMB1);
    }
}

extern "C" void kernel_launch(void* const* d_in, const int* in_sizes, int n_in,
                              void* d_out, int out_size, void* d_ws, size_t ws_size,
                              hipStream_t stream) {
    const float* x      = (const float*)d_in[0];   // [8192,128]
    const float* Wc     = (const float*)d_in[1];   // [4,128]
    const float* sscore = (const float*)d_in[2];   // [256]
    // d_in[3] selected_batch (derivable), d_in[4] selected_mapping,
    // d_in[5] selected_belong (derivable), d_in[6] full_edge_index (block-diag, implicit)
    const int* smap = (const int*)d_in[4];         // [8192]
    const int* rei  = (const int*)d_in[7];         // [2, 262144]
    float* out = (float*)d_out;

    // 1) zero the dense 12288^2 output (the HBM-write floor)
    hipMemsetAsync(out, 0, (size_t)out_size * sizeof(float), stream);

    // 2) intra-subgraph weighted-cosine blocks -> unique plain stores
    subgraph_kernel<<<N_SUB, 256, 0, stream>>>(x, Wc, sscore, smap, out);

    // 3) raw-edge coalesce: atomic +0.5 (handles duplicates + overlaps)
    raw_edge_kernel<<<E_RAW / 256, 256, 0, stream>>>(rei, out);
}